// Round 18
// baseline (185.215 us; speedup 1.0000x reference)
//
#include <hip/hip_runtime.h>
#include <cstdint>

// ---------------- problem constants ----------------
#define D_MODEL 1024
#define NHEADS  16
#define DKH     64
#define DEXT    80          // augmented head dim: 64 Q/K + 8 one-hot bias + 1 mask + 7 pad
#define SEQ     2048
#define NBATCH  2
#define MROWS   (NBATCH*SEQ)   // 4096
#define RTYPES  8
#define LOG2E   1.44269504f

typedef __bf16 bf16;
typedef __bf16 bf16x4v __attribute__((ext_vector_type(4)));
typedef __bf16 bf16x8v __attribute__((ext_vector_type(8)));
typedef float  f32x4v  __attribute__((ext_vector_type(4)));
typedef float  f32x16v __attribute__((ext_vector_type(16)));

typedef unsigned int __attribute__((address_space(1))) as1_u32;
typedef unsigned int __attribute__((address_space(3))) as3_u32;

static __device__ __forceinline__ void gload_lds16(const void* g, void* l) {
  __builtin_amdgcn_global_load_lds((const as1_u32*)(uintptr_t)g,
                                   (as3_u32*)(uintptr_t)l, 16, 0, 0);
}

static __device__ __forceinline__ f32x4v mfma16(bf16x8v a, bf16x8v b, f32x4v c) {
  return __builtin_amdgcn_mfma_f32_16x16x32_bf16(a, b, c, 0, 0, 0);
}
static __device__ __forceinline__ f32x16v mfma32(bf16x8v a, bf16x8v b, f32x16v c) {
  return __builtin_amdgcn_mfma_f32_32x32x16_bf16(a, b, c, 0, 0, 0);
}

// XCD-aware bijective remap (T1, m204): nwg must be a multiple of 8.
static __device__ __forceinline__ int xcd_swizzle(int flat, int nwg){
  const int per = nwg >> 3;            // nwg % 8 == 0
  return (flat & 7) * per + (flat >> 3);
}

// ---------------- fp32->bf16 conversion (x + 4 weights), 32B/thread ------------
__global__ void convert_kernel(const float* __restrict__ x,  const float* __restrict__ wq,
                               const float* __restrict__ wk, const float* __restrict__ wv,
                               const float* __restrict__ wo,
                               bf16* __restrict__ xb,  bf16* __restrict__ wqb,
                               bf16* __restrict__ wkb, bf16* __restrict__ wvb,
                               bf16* __restrict__ wob)
{
  int idx = blockIdx.x*256 + threadIdx.x;
  const float* src; bf16* dst; int i;
  if (idx < 524288){ src = x; dst = xb; i = idx; }
  else {
    int off = idx - 524288;
    int r = off >> 17;                 // 0..3
    i = off & 131071;
    if (r == 0)      { src = wq; dst = wqb; }
    else if (r == 1) { src = wk; dst = wkb; }
    else if (r == 2) { src = wv; dst = wvb; }
    else             { src = wo; dst = wob; }
  }
  float4 v0 = ((const float4*)src)[2*i];
  float4 v1 = ((const float4*)src)[2*i+1];
  bf16x8v o;
  o[0]=(bf16)v0.x; o[1]=(bf16)v0.y; o[2]=(bf16)v0.z; o[3]=(bf16)v0.w;
  o[4]=(bf16)v1.x; o[5]=(bf16)v1.y; o[6]=(bf16)v1.z; o[7]=(bf16)v1.w;
  ((bf16x8v*)dst)[i] = o;
}

// ---------------- fused QKV GEMM + ext-fill, 2-phase dbuf, XCD-swizzled --------
// blocks <768 = GEMM (n-tile 8 | m-tile 32 | z 3, swizzled); >=768 = ext-fill.
// z<2 (Q,K): SWAPPED MFMA operands (A=W, B=x) -> lane regs = 4 consecutive dk
//   -> vectorized b64 epilogue stores (was 64 scalar b16 stores/thread).
// z=2 (V^T): original orientation (m-consecutive regs -> b64 along s).
struct GemmOuts { const bf16* W[3]; const float* bia[3]; void* out[3]; };

__global__ __launch_bounds__(256, 3) void gemm_qkv_kernel(
    const bf16* __restrict__ A, GemmOuts args, float qscale,
    const float* __restrict__ rbias, const int* __restrict__ rmask,
    const int* __restrict__ amask, bf16* __restrict__ qext, bf16* __restrict__ kext)
{
  if (blockIdx.x >= 768){
    int i = (blockIdx.x - 768)*256 + threadIdx.x;   // 0..131071
    int s  = i & 2047;
    int hh = (i>>11) & 15;
    int bb = (i>>15) & 1;
    int which = i >> 16;              // 0 = Q ext, 1 = K ext
    int t  = rmask[bb*SEQ + s];
    int am = amask[bb*SEQ + s];
    bf16* dst = (which==0 ? qext : kext)
              + ((size_t)(bb*NHEADS + hh)*SEQ + s)*DEXT + 64;
    bf16x8v lo, hi2;
    if (which == 0){
      #pragma unroll
      for (int r=0;r<8;r++) lo[r] = (bf16)(rbias[(hh*RTYPES + t)*RTYPES + r] * LOG2E);
      #pragma unroll
      for (int r=0;r<8;r++) hi2[r] = (bf16)0.f;
      hi2[0] = (bf16)(-1048576.0f);
    } else {
      #pragma unroll
      for (int r=0;r<8;r++) lo[r] = (bf16)((t==r) ? 1.f : 0.f);
      #pragma unroll
      for (int r=0;r<8;r++) hi2[r] = (bf16)0.f;
      hi2[0] = am ? (bf16)0.f : (bf16)1.0f;
    }
    *(bf16x8v*)dst       = lo;
    *(bf16x8v*)(dst + 8) = hi2;
    return;
  }

  const int K  = D_MODEL;
  const int wg = xcd_swizzle(blockIdx.x, 768);
  const int z  = wg >> 8;
  const bf16*  Bw   = args.W[z];
  const float* bias = args.bia[z];
  void* outp        = args.out[z];
  const float scale = (z==0) ? qscale : 1.0f;

  const int n0 = (wg & 7)*128, m0 = ((wg>>3) & 31)*128;
  const int tid = threadIdx.x;
  const int w = tid>>6, lane = tid&63, g = lane>>4, c = lane&15;
  const int wm = w>>1, wn = w&1;

  __shared__ __align__(16) bf16 a_lds[2][128*32];
  __shared__ __align__(16) bf16 b_lds[2][128*32];

  const f32x4v fzero = {0.f,0.f,0.f,0.f};
  f32x4v acc[4][4];
  for (int i=0;i<4;i++) for (int j=0;j<4;j++) acc[i][j] = fzero;

  const int srow = tid>>2, sc8 = tid&3;

  auto STAGE = [&](int k0, int nb){
    gload_lds16(A  + (size_t)(m0+srow)*K     + k0 + sc8*8, &a_lds[nb][(w*64)*8]);
    gload_lds16(Bw + (size_t)(n0+srow)*K     + k0 + sc8*8, &b_lds[nb][(w*64)*8]);
    gload_lds16(A  + (size_t)(m0+64+srow)*K  + k0 + sc8*8, &a_lds[nb][(256 + w*64)*8]);
    gload_lds16(Bw + (size_t)(n0+64+srow)*K  + k0 + sc8*8, &b_lds[nb][(256 + w*64)*8]);
  };

  auto COMPUTE = [&](int nb){
    bf16x8v af[4], bfv[4];
    #pragma unroll
    for (int mt=0;mt<4;mt++)
      af[mt] = *(const bf16x8v*)&a_lds[nb][(wm*64 + mt*16 + c)*32 + g*8];
    #pragma unroll
    for (int nt=0;nt<4;nt++)
      bfv[nt] = *(const bf16x8v*)&b_lds[nb][(wn*64 + nt*16 + c)*32 + g*8];
    if (z == 2){
      #pragma unroll
      for (int mt=0;mt<4;mt++)
        #pragma unroll
        for (int nt=0;nt<4;nt++)
          acc[mt][nt] = mfma16(af[mt], bfv[nt], acc[mt][nt]);
    } else {
      // swapped: A=W (rows n), B=x (cols m) -> D rows = n, cols = m
      #pragma unroll
      for (int mt=0;mt<4;mt++)
        #pragma unroll
        for (int nt=0;nt<4;nt++)
          acc[mt][nt] = mfma16(bfv[nt], af[mt], acc[mt][nt]);
    }
  };

  STAGE(0, 0);
  __syncthreads();
  int cur = 0;
  for (int k0=32; k0<K; k0+=32){
    STAGE(k0, cur^1);
    COMPUTE(cur);
    __syncthreads();
    cur ^= 1;
  }
  COMPUTE(cur);

  #pragma unroll
  for (int mt=0;mt<4;mt++){
    #pragma unroll
    for (int nt=0;nt<4;nt++){
      if (z == 2){
        int m = m0 + wm*64 + mt*16 + g*4;
        int n = n0 + wn*64 + nt*16 + c;
        int bb=m>>11, s=m&2047, hh=n>>6, dk=n&63;
        float bn = bias[n];
        bf16x4v ov;
        #pragma unroll
        for (int r=0;r<4;r++) ov[r] = (bf16)(acc[mt][nt][r] + bn);
        *(bf16x4v*)&((bf16*)outp)[(((size_t)bb*NHEADS+hh)*DKH + dk)*SEQ + s] = ov;
      } else {
        // swapped layout: lane holds out[m = ..+c][n = ..+g*4+0..3]
        int m  = m0 + wm*64 + mt*16 + c;
        int nb_= n0 + wn*64 + nt*16 + g*4;
        f32x4v b4 = *(const f32x4v*)&bias[nb_];
        int bb=m>>11, s=m&2047, hh=nb_>>6, dk=nb_&63;
        bf16x4v ov;
        #pragma unroll
        for (int r=0;r<4;r++) ov[r] = (bf16)((acc[mt][nt][r] + b4[r]) * scale);
        *(bf16x4v*)&((bf16*)outp)[(((size_t)bb*NHEADS+hh)*SEQ + s)*DEXT + dk] = ov;
      }
    }
  }
}

// ---------------- out-projection GEMM: 128x64 tiles, XCD-swizzled -------------
__global__ __launch_bounds__(256, 2) void gemm_out_kernel(
    const bf16* __restrict__ A, const bf16* __restrict__ Bw,
    const float* __restrict__ bias, float* __restrict__ outp)
{
  const int K  = D_MODEL;
  const int wg = xcd_swizzle(blockIdx.x, 512);
  const int n0 = (wg & 15)*64, m0 = (wg >> 4)*128;
  const int tid = threadIdx.x;
  const int w = tid>>6, lane = tid&63, g = lane>>4, c = lane&15;
  const int wm = w>>1, wn = w&1;

  __shared__ __align__(16) bf16 a_lds[2][128*32];   // 8 KB each buf
  __shared__ __align__(16) bf16 b_lds[2][64*32];    // 4 KB each buf

  const f32x4v fzero = {0.f,0.f,0.f,0.f};
  f32x4v acc[4][2];
  for (int i=0;i<4;i++) for (int j=0;j<2;j++) acc[i][j] = fzero;

  const int srow = tid>>2, sc8 = tid&3;

  auto STAGE = [&](int k0, int nb){
    gload_lds16(A  + (size_t)(m0+srow)*K     + k0 + sc8*8, &a_lds[nb][(w*64)*8]);
    gload_lds16(A  + (size_t)(m0+64+srow)*K  + k0 + sc8*8, &a_lds[nb][(256 + w*64)*8]);
    gload_lds16(Bw + (size_t)(n0+srow)*K     + k0 + sc8*8, &b_lds[nb][(w*64)*8]);
  };

  auto COMPUTE = [&](int nb){
    bf16x8v af[4], bfv[2];
    #pragma unroll
    for (int mt=0;mt<4;mt++)
      af[mt] = *(const bf16x8v*)&a_lds[nb][(wm*64 + mt*16 + c)*32 + g*8];
    #pragma unroll
    for (int nt=0;nt<2;nt++)
      bfv[nt] = *(const bf16x8v*)&b_lds[nb][(wn*32 + nt*16 + c)*32 + g*8];
    #pragma unroll
    for (int mt=0;mt<4;mt++)
      #pragma unroll
      for (int nt=0;nt<2;nt++)
        acc[mt][nt] = mfma16(af[mt], bfv[nt], acc[mt][nt]);
  };

  STAGE(0, 0);
  __syncthreads();
  int cur = 0;
  for (int k0=32; k0<K; k0+=32){
    STAGE(k0, cur^1);
    COMPUTE(cur);
    __syncthreads();
    cur ^= 1;
  }
  COMPUTE(cur);

  #pragma unroll
  for (int mt=0;mt<4;mt++){
    #pragma unroll
    for (int nt=0;nt<2;nt++){
      #pragma unroll
      for (int r=0;r<4;r++){
        int m = m0 + wm*64 + mt*16 + g*4 + r;
        int n = n0 + wn*32 + nt*16 + c;
        outp[(size_t)m*D_MODEL + n] = acc[mt][nt][r] + bias[n];
      }
    }
  }
}

// ---------------- flash attention v13: V direct-from-global (no V staging) -----
// v10 structure (DEXT=80 bias-fold, j-split 8 waves, sigma K staging, d-major
// conflict-free K LDS, 2-buffer loop, no-max exp2 softmax, T1, T5) with the V
// LDS datapath REMOVED (Common-mistake #7 / m169): V frags are per-lane global
// b128 loads issued at tile start (T14 early-issue; ~700cy of QK+softmax hides
// L2 latency). The 4 waves per half read identical addresses -> L1 absorbs the
// redundancy. LDS reads/wave-tile 18->10; staging loads/thread ~5->~3; LDS 40KB.
__global__ __launch_bounds__(512, 4) void attn13_kernel(
    const bf16* __restrict__ Qg, const bf16* __restrict__ Kg,
    const bf16* __restrict__ Vtg, bf16* __restrict__ Og)
{
  const int wg = xcd_swizzle(blockIdx.x, 512);
  const int q0 = (wg & 15)*128;
  const int h  = (wg >> 4) & 15;
  const int b  = wg >> 8;
  const int tid = threadIdx.x;
  const int w = tid>>6, lane = tid&63;
  const int half = w>>2, wl = w&3;
  const int q5 = lane&31, hi = lane>>5;
  const int bh = b*NHEADS + h;
  const int NTl = 16;                          // tiles per half

  __shared__ __align__(16) bf16 k_lds[2][2][5120];   // 10 d-slabs x 64 rows x 8

  const int qrow = q0 + wl*32 + q5;
  const bf16* qptr = Qg + ((size_t)bh*SEQ + qrow)*DEXT;
  bf16x8v qf[5];
  #pragma unroll
  for (int kc=0;kc<5;kc++)
    qf[kc] = *(const bf16x8v*)(qptr + kc*16 + hi*8);

  f32x16v oacc0, oacc1;
  #pragma unroll
  for (int r=0;r<16;r++){ oacc0[r]=0.f; oacc1[r]=0.f; }
  float lrow = 0.f;

  const int sig = (lane & 0x33) | ((lane & 8) >> 1) | ((lane & 4) << 1);
  const bf16* ksrcL = Kg  + ((size_t)bh*SEQ + sig)*DEXT;
  // V direct-read bases: lane reads V^T rows d=q5 (oacc0) and d=32+q5 (oacc1)
  const bf16* vbase0 = Vtg + ((size_t)bh*DKH + q5)*SEQ;
  const bf16* vbase1 = Vtg + ((size_t)bh*DKH + 32 + q5)*SEQ;
  const int jb0 = half*1024;
  const int lbase = hi*512 + q5*8;

  auto STAGE = [&](int t, int nb){
    const int j0 = jb0 + t*64;
    const size_t joff = (size_t)j0*DEXT;
    gload_lds16(ksrcL + joff + wl*8,       &k_lds[half][nb][wl*512]);
    gload_lds16(ksrcL + joff + (wl+4)*8,   &k_lds[half][nb][(wl+4)*512]);
    if (wl < 2)
      gload_lds16(ksrcL + joff + (8+wl)*8, &k_lds[half][nb][(8+wl)*512]);
  };

  auto COMPUTE = [&](int nb, int j0){
    const bf16* kb_ = &k_lds[half][nb][0];

    // early V prefetch (T14): issued before QK so QK+softmax hides latency
    bf16x8v vp0[4], vp1[4];
    #pragma unroll
    for (int m=0;m<4;m++){
      vp0[m] = *(const bf16x8v*)(vbase0 + j0 + m*16 + hi*8);
      vp1[m] = *(const bf16x8v*)(vbase1 + j0 + m*16 + hi*8);
    }

    f32x16v s0, s1;
    #pragma unroll
    for (int r=0;r<16;r++){ s0[r]=0.f; s1[r]=0.f; }
    __builtin_amdgcn_s_setprio(1);
    #pragma unroll
    for (int kc=0;kc<5;kc++){
      bf16x8v kf0 = *(const bf16x8v*)(kb_ + lbase + kc*1024);
      bf16x8v kf1 = *(const bf16x8v*)(kb_ + lbase + kc*1024 + 256);
      s0 = mfma32(kf0, qf[kc], s0);
      s1 = mfma32(kf1, qf[kc], s1);
    }
    __builtin_amdgcn_s_setprio(0);

    #pragma unroll
    for (int r=0;r<16;r++){ s0[r] = exp2f(s0[r]); s1[r] = exp2f(s1[r]); }

    float t0 = 0.f, t1 = 0.f;
    #pragma unroll
    for (int r=0;r<16;r++){ t0 += s0[r]; t1 += s1[r]; }
    float sum = t0 + t1;
    sum += __shfl_xor(sum, 32);
    lrow += sum;

    bf16x8v pa0, pa1, pa2, pa3;
    #pragma unroll
    for (int e=0;e<8;e++){
      pa0[e] = (bf16)s0[e];   pa1[e] = (bf16)s0[e+8];
      pa2[e] = (bf16)s1[e];   pa3[e] = (bf16)s1[e+8];
    }

    __builtin_amdgcn_s_setprio(1);
    #pragma unroll
    for (int m=0;m<4;m++){
      bf16x8v pm = (m==0)?pa0:(m==1)?pa1:(m==2)?pa2:pa3;
      oacc0 = mfma32(vp0[m], pm, oacc0);
      oacc1 = mfma32(vp1[m], pm, oacc1);
    }
    __builtin_amdgcn_s_setprio(0);
  };

  STAGE(0, 0);
  __syncthreads();
  int cur = 0;
  #pragma unroll 1
  for (int t=0; t<NTl; ++t){
    if (t+1 < NTl) STAGE(t+1, cur^1);
    COMPUTE(cur, jb0 + t*64);
    __syncthreads();
    cur ^= 1;
  }

  // ---- in-block merge (plain sum; overlay k_lds: 40960B >= 34816B needed) ----
  float* mrg = (float*)&k_lds[0][0][0];    // [q-row][68]: 64 O + l
  if (half == 1){
    float* row = mrg + (wl*32 + q5)*68;
    #pragma unroll
    for (int rq=0;rq<4;rq++){
      f32x4v t0v, t1v;
      #pragma unroll
      for (int k=0;k<4;k++){ t0v[k] = oacc0[rq*4+k]; t1v[k] = oacc1[rq*4+k]; }
      *(f32x4v*)(row + 0  + rq*8 + hi*4) = t0v;
      *(f32x4v*)(row + 32 + rq*8 + hi*4) = t1v;
    }
    if (hi == 0) row[64] = lrow;
  }
  __syncthreads();
  if (half == 0){
    const float* row = mrg + (wl*32 + q5)*68;
    const float inv = 1.0f / (lrow + row[64]);
    bf16* orow = &Og[(size_t)(b*SEQ + qrow)*D_MODEL + h*DKH];
    #pragma unroll
    for (int rq=0;rq<4;rq++){
      f32x4v o1a = *(const f32x4v*)(row + 0  + rq*8 + hi*4);
      f32x4v o1b = *(const f32x4v*)(row + 32 + rq*8 + hi*4);
      bf16x4v ov0, ov1;
      #pragma unroll
      for (int k=0;k<4;k++){
        ov0[k] = (bf16)((oacc0[rq*4+k] + o1a[k]) * inv);
        ov1[k] = (bf16)((oacc1[rq*4+k] + o1b[k]) * inv);
      }
      const int d = 8*rq + 4*hi;
      *(bf16x4v*)(orow + d)      = ov0;
      *(bf16x4v*)(orow + 32 + d) = ov1;
    }
  }
}

// ---------------- launch ----------------
extern "C" void kernel_launch(void* const* d_in, const int* in_sizes, int n_in,
                              void* d_out, int out_size, void* d_ws, size_t ws_size,
                              hipStream_t stream)
{
  (void)in_sizes; (void)n_in; (void)out_size; (void)ws_size;
  const float* x     = (const float*)d_in[0];
  const float* Wq    = (const float*)d_in[1];
  const float* bq    = (const float*)d_in[2];
  const float* Wk    = (const float*)d_in[3];
  const float* bk    = (const float*)d_in[4];
  const float* Wv    = (const float*)d_in[5];
  const float* bv    = (const float*)d_in[6];
  const float* Wo    = (const float*)d_in[7];
  const float* bo    = (const float*)d_in[8];
  const float* rbias = (const float*)d_in[9];
  const int*   rmask = (const int*)d_in[10];
  const int*   amask = (const int*)d_in[11];
  float* out = (float*)d_out;

  char* ws = (char*)d_ws;
  bf16*  xb    = (bf16*)(ws);                 //  8 MB
  bf16*  wqb   = (bf16*)(ws + (8u<<20));      //  2 MB each
  bf16*  wkb   = (bf16*)(ws + (10u<<20));
  bf16*  wvb   = (bf16*)(ws + (12u<<20));
  bf16*  wob   = (bf16*)(ws + (14u<<20));
  bf16*  qb    = (bf16*)(ws + (16u<<20));     // 10 MB Q' [b][h][s][80]
  bf16*  kb    = (bf16*)(ws + (27u<<20));     // 10 MB K' [b][h][s][80]
  bf16*  vtb   = (bf16*)(ws + (38u<<20));     //  8 MB V^T [b][h][dk][s]
  bf16*  aob   = (bf16*)(ws + (46u<<20));     //  8 MB attn out [s][e]

  convert_kernel<<<4096, 256, 0, stream>>>(x,Wq,Wk,Wv,Wo, xb,wqb,wkb,wvb,wob);

  GemmOuts qkv;
  qkv.W[0]=wqb; qkv.W[1]=wkb; qkv.W[2]=wvb;
  qkv.bia[0]=bq; qkv.bia[1]=bk; qkv.bia[2]=bv;
  qkv.out[0]=qb; qkv.out[1]=kb; qkv.out[2]=vtb;
  gemm_qkv_kernel<<<1280, 256, 0, stream>>>(xb, qkv, 0.125f*LOG2E,
                                            rbias, rmask, amask, qb, kb);

  attn13_kernel<<<512, 512, 0, stream>>>(qb, kb, vtb, aob);

  gemm_out_kernel<<<512, 256, 0, stream>>>(aob, wob, bo, out);
}

// Round 19
// 120.856 us; speedup vs baseline: 1.5325x; 1.5325x over previous
//
#include <hip/hip_runtime.h>
#include <cstdint>

// ---------------- problem constants ----------------
#define D_MODEL 1024
#define NHEADS  16
#define DKH     64
#define DEXT    80          // augmented head dim: 64 Q/K + 8 one-hot bias + 1 mask + 7 pad
#define SEQ     2048
#define NBATCH  2
#define MROWS   (NBATCH*SEQ)   // 4096
#define RTYPES  8
#define LOG2E   1.44269504f

typedef __bf16 bf16;
typedef __bf16 bf16x4v __attribute__((ext_vector_type(4)));
typedef __bf16 bf16x8v __attribute__((ext_vector_type(8)));
typedef float  f32x4v  __attribute__((ext_vector_type(4)));
typedef float  f32x16v __attribute__((ext_vector_type(16)));

typedef unsigned int __attribute__((address_space(1))) as1_u32;
typedef unsigned int __attribute__((address_space(3))) as3_u32;

static __device__ __forceinline__ void gload_lds16(const void* g, void* l) {
  __builtin_amdgcn_global_load_lds((const as1_u32*)(uintptr_t)g,
                                   (as3_u32*)(uintptr_t)l, 16, 0, 0);
}

static __device__ __forceinline__ f32x4v mfma16(bf16x8v a, bf16x8v b, f32x4v c) {
  return __builtin_amdgcn_mfma_f32_16x16x32_bf16(a, b, c, 0, 0, 0);
}
static __device__ __forceinline__ f32x16v mfma32(bf16x8v a, bf16x8v b, f32x16v c) {
  return __builtin_amdgcn_mfma_f32_32x32x16_bf16(a, b, c, 0, 0, 0);
}

// XCD-aware bijective remap (T1, m204): nwg must be a multiple of 8.
static __device__ __forceinline__ int xcd_swizzle(int flat, int nwg){
  const int per = nwg >> 3;            // nwg % 8 == 0
  return (flat & 7) * per + (flat >> 3);
}

// ---------------- fp32->bf16 conversion (x + 4 weights), 32B/thread ------------
__global__ void convert_kernel(const float* __restrict__ x,  const float* __restrict__ wq,
                               const float* __restrict__ wk, const float* __restrict__ wv,
                               const float* __restrict__ wo,
                               bf16* __restrict__ xb,  bf16* __restrict__ wqb,
                               bf16* __restrict__ wkb, bf16* __restrict__ wvb,
                               bf16* __restrict__ wob)
{
  int idx = blockIdx.x*256 + threadIdx.x;
  const float* src; bf16* dst; int i;
  if (idx < 524288){ src = x; dst = xb; i = idx; }
  else {
    int off = idx - 524288;
    int r = off >> 17;                 // 0..3
    i = off & 131071;
    if (r == 0)      { src = wq; dst = wqb; }
    else if (r == 1) { src = wk; dst = wkb; }
    else if (r == 2) { src = wv; dst = wvb; }
    else             { src = wo; dst = wob; }
  }
  float4 v0 = ((const float4*)src)[2*i];
  float4 v1 = ((const float4*)src)[2*i+1];
  bf16x8v o;
  o[0]=(bf16)v0.x; o[1]=(bf16)v0.y; o[2]=(bf16)v0.z; o[3]=(bf16)v0.w;
  o[4]=(bf16)v1.x; o[5]=(bf16)v1.y; o[6]=(bf16)v1.z; o[7]=(bf16)v1.w;
  ((bf16x8v*)dst)[i] = o;
}

// ---------------- fused QKV GEMM + ext-fill, 2-phase dbuf, XCD-swizzled --------
// flat grid 1280: blocks <768 = GEMM (n-tile 8 | m-tile 32 | z 3, swizzled);
// blocks >=768 = Q'/K' extension-column fill (cols 64..79, disjoint from GEMM's
// cols 0..63 -> no race, hides under the GEMM tail).
struct GemmOuts { const bf16* W[3]; const float* bia[3]; void* out[3]; };

__global__ __launch_bounds__(256, 3) void gemm_qkv_kernel(
    const bf16* __restrict__ A, GemmOuts args, float qscale,
    const float* __restrict__ rbias, const int* __restrict__ rmask,
    const int* __restrict__ amask, bf16* __restrict__ qext, bf16* __restrict__ kext)
{
  if (blockIdx.x >= 768){
    int i = (blockIdx.x - 768)*256 + threadIdx.x;   // 0..131071
    int s  = i & 2047;
    int hh = (i>>11) & 15;
    int bb = (i>>15) & 1;
    int which = i >> 16;              // 0 = Q ext, 1 = K ext
    int t  = rmask[bb*SEQ + s];
    int am = amask[bb*SEQ + s];
    bf16* dst = (which==0 ? qext : kext)
              + ((size_t)(bb*NHEADS + hh)*SEQ + s)*DEXT + 64;
    bf16x8v lo, hi2;
    if (which == 0){
      #pragma unroll
      for (int r=0;r<8;r++) lo[r] = (bf16)(rbias[(hh*RTYPES + t)*RTYPES + r] * LOG2E);
      #pragma unroll
      for (int r=0;r<8;r++) hi2[r] = (bf16)0.f;
      hi2[0] = (bf16)(-1048576.0f);
    } else {
      #pragma unroll
      for (int r=0;r<8;r++) lo[r] = (bf16)((t==r) ? 1.f : 0.f);
      #pragma unroll
      for (int r=0;r<8;r++) hi2[r] = (bf16)0.f;
      hi2[0] = am ? (bf16)0.f : (bf16)1.0f;
    }
    *(bf16x8v*)dst       = lo;
    *(bf16x8v*)(dst + 8) = hi2;
    return;
  }

  const int K  = D_MODEL;
  const int wg = xcd_swizzle(blockIdx.x, 768);
  const int z  = wg >> 8;
  const bf16*  Bw   = args.W[z];
  const float* bias = args.bia[z];
  void* outp        = args.out[z];
  const float scale = (z==0) ? qscale : 1.0f;

  const int n0 = (wg & 7)*128, m0 = ((wg>>3) & 31)*128;
  const int tid = threadIdx.x;
  const int w = tid>>6, lane = tid&63, g = lane>>4, c = lane&15;
  const int wm = w>>1, wn = w&1;

  __shared__ __align__(16) bf16 a_lds[2][128*32];
  __shared__ __align__(16) bf16 b_lds[2][128*32];

  const f32x4v fzero = {0.f,0.f,0.f,0.f};
  f32x4v acc[4][4];
  for (int i=0;i<4;i++) for (int j=0;j<4;j++) acc[i][j] = fzero;

  const int srow = tid>>2, sc8 = tid&3;

  auto STAGE = [&](int k0, int nb){
    gload_lds16(A  + (size_t)(m0+srow)*K     + k0 + sc8*8, &a_lds[nb][(w*64)*8]);
    gload_lds16(Bw + (size_t)(n0+srow)*K     + k0 + sc8*8, &b_lds[nb][(w*64)*8]);
    gload_lds16(A  + (size_t)(m0+64+srow)*K  + k0 + sc8*8, &a_lds[nb][(256 + w*64)*8]);
    gload_lds16(Bw + (size_t)(n0+64+srow)*K  + k0 + sc8*8, &b_lds[nb][(256 + w*64)*8]);
  };

  auto COMPUTE = [&](int nb){
    bf16x8v af[4], bfv[4];
    #pragma unroll
    for (int mt=0;mt<4;mt++)
      af[mt] = *(const bf16x8v*)&a_lds[nb][(wm*64 + mt*16 + c)*32 + g*8];
    #pragma unroll
    for (int nt=0;nt<4;nt++)
      bfv[nt] = *(const bf16x8v*)&b_lds[nb][(wn*64 + nt*16 + c)*32 + g*8];
    #pragma unroll
    for (int mt=0;mt<4;mt++)
      #pragma unroll
      for (int nt=0;nt<4;nt++)
        acc[mt][nt] = mfma16(af[mt], bfv[nt], acc[mt][nt]);
  };

  STAGE(0, 0);
  __syncthreads();
  int cur = 0;
  for (int k0=32; k0<K; k0+=32){
    STAGE(k0, cur^1);
    COMPUTE(cur);
    __syncthreads();
    cur ^= 1;
  }
  COMPUTE(cur);

  #pragma unroll
  for (int mt=0;mt<4;mt++){
    #pragma unroll
    for (int nt=0;nt<4;nt++){
      if (z == 2){
        int m = m0 + wm*64 + mt*16 + g*4;
        int n = n0 + wn*64 + nt*16 + c;
        int bb=m>>11, s=m&2047, hh=n>>6, dk=n&63;
        float bn = bias[n];
        bf16x4v ov;
        #pragma unroll
        for (int r=0;r<4;r++) ov[r] = (bf16)(acc[mt][nt][r] + bn);
        *(bf16x4v*)&((bf16*)outp)[(((size_t)bb*NHEADS+hh)*DKH + dk)*SEQ + s] = ov;
      } else {
        #pragma unroll
        for (int r=0;r<4;r++){
          int m = m0 + wm*64 + mt*16 + g*4 + r;
          int n = n0 + wn*64 + nt*16 + c;
          float v = (acc[mt][nt][r] + bias[n]) * scale;
          int bb=m>>11, s=m&2047, hh=n>>6, dk=n&63;
          ((bf16*)outp)[(((size_t)bb*NHEADS+hh)*SEQ + s)*DEXT + dk] = (bf16)v;
        }
      }
    }
  }
}

// ---------------- out-projection GEMM: 128x64 tiles, XCD-swizzled -------------
__global__ __launch_bounds__(256, 2) void gemm_out_kernel(
    const bf16* __restrict__ A, const bf16* __restrict__ Bw,
    const float* __restrict__ bias, float* __restrict__ outp)
{
  const int K  = D_MODEL;
  const int wg = xcd_swizzle(blockIdx.x, 512);
  const int n0 = (wg & 15)*64, m0 = (wg >> 4)*128;
  const int tid = threadIdx.x;
  const int w = tid>>6, lane = tid&63, g = lane>>4, c = lane&15;
  const int wm = w>>1, wn = w&1;

  __shared__ __align__(16) bf16 a_lds[2][128*32];   // 8 KB each buf
  __shared__ __align__(16) bf16 b_lds[2][64*32];    // 4 KB each buf

  const f32x4v fzero = {0.f,0.f,0.f,0.f};
  f32x4v acc[4][2];
  for (int i=0;i<4;i++) for (int j=0;j<2;j++) acc[i][j] = fzero;

  const int srow = tid>>2, sc8 = tid&3;

  auto STAGE = [&](int k0, int nb){
    gload_lds16(A  + (size_t)(m0+srow)*K     + k0 + sc8*8, &a_lds[nb][(w*64)*8]);
    gload_lds16(A  + (size_t)(m0+64+srow)*K  + k0 + sc8*8, &a_lds[nb][(256 + w*64)*8]);
    gload_lds16(Bw + (size_t)(n0+srow)*K     + k0 + sc8*8, &b_lds[nb][(w*64)*8]);
  };

  auto COMPUTE = [&](int nb){
    bf16x8v af[4], bfv[2];
    #pragma unroll
    for (int mt=0;mt<4;mt++)
      af[mt] = *(const bf16x8v*)&a_lds[nb][(wm*64 + mt*16 + c)*32 + g*8];
    #pragma unroll
    for (int nt=0;nt<2;nt++)
      bfv[nt] = *(const bf16x8v*)&b_lds[nb][(wn*32 + nt*16 + c)*32 + g*8];
    #pragma unroll
    for (int mt=0;mt<4;mt++)
      #pragma unroll
      for (int nt=0;nt<2;nt++)
        acc[mt][nt] = mfma16(af[mt], bfv[nt], acc[mt][nt]);
  };

  STAGE(0, 0);
  __syncthreads();
  int cur = 0;
  for (int k0=32; k0<K; k0+=32){
    STAGE(k0, cur^1);
    COMPUTE(cur);
    __syncthreads();
    cur ^= 1;
  }
  COMPUTE(cur);

  #pragma unroll
  for (int mt=0;mt<4;mt++){
    #pragma unroll
    for (int nt=0;nt<2;nt++){
      #pragma unroll
      for (int r=0;r<4;r++){
        int m = m0 + wm*64 + mt*16 + g*4 + r;
        int n = n0 + wn*32 + nt*16 + c;
        outp[(size_t)m*D_MODEL + n] = acc[mt][nt][r] + bias[n];
      }
    }
  }
}

// ---------------- flash attention v10 (best-measured variant) ----------------
// Bias folded into QK^T via DEXT=80; j-split 8 waves; d-major conflict-free LDS;
// sigma staging; 2-buffer loop; P = exp2(s) directly (scores bounded, masked->0);
// merge = plain sum; T1 swizzle; T5 setprio around MFMA clusters.
__global__ __launch_bounds__(512, 4) void attn10_kernel(
    const bf16* __restrict__ Qg, const bf16* __restrict__ Kg,
    const bf16* __restrict__ Vtg, bf16* __restrict__ Og)
{
  const int wg = xcd_swizzle(blockIdx.x, 512);
  const int q0 = (wg & 15)*128;
  const int h  = (wg >> 4) & 15;
  const int b  = wg >> 8;
  const int tid = threadIdx.x;
  const int w = tid>>6, lane = tid&63;
  const int half = w>>2, wl = w&3;
  const int q5 = lane&31, hi = lane>>5;
  const int bh = b*NHEADS + h;
  const int NTl = 16;                          // tiles per half

  __shared__ __align__(16) bf16 k_lds[2][2][5120];   // 10 d-slabs x 64 rows x 8
  __shared__ __align__(16) bf16 v_lds[2][2][4096];   //  8 j-slabs x 64 rows x 8

  const int qrow = q0 + wl*32 + q5;
  const bf16* qptr = Qg + ((size_t)bh*SEQ + qrow)*DEXT;
  bf16x8v qf[5];
  #pragma unroll
  for (int kc=0;kc<5;kc++)
    qf[kc] = *(const bf16x8v*)(qptr + kc*16 + hi*8);

  f32x16v oacc0, oacc1;
  #pragma unroll
  for (int r=0;r<16;r++){ oacc0[r]=0.f; oacc1[r]=0.f; }
  float lrow = 0.f;

  const int sig = (lane & 0x33) | ((lane & 8) >> 1) | ((lane & 4) << 1);
  const bf16* ksrcL = Kg  + ((size_t)bh*SEQ + sig)*DEXT;
  const bf16* vsrcL = Vtg + ((size_t)bh*DKH + lane)*SEQ;
  const int jb0 = half*1024;
  const int lbase = hi*512 + q5*8;

  auto STAGE = [&](int t, int nb){
    const int j0 = jb0 + t*64;
    const size_t joff = (size_t)j0*DEXT;
    gload_lds16(ksrcL + joff + wl*8,       &k_lds[half][nb][wl*512]);
    gload_lds16(ksrcL + joff + (wl+4)*8,   &k_lds[half][nb][(wl+4)*512]);
    if (wl < 2)
      gload_lds16(ksrcL + joff + (8+wl)*8, &k_lds[half][nb][(8+wl)*512]);
    gload_lds16(vsrcL + j0 + wl*8,         &v_lds[half][nb][wl*512]);
    gload_lds16(vsrcL + j0 + (wl+4)*8,     &v_lds[half][nb][(wl+4)*512]);
  };

  auto COMPUTE = [&](int nb){
    const bf16* kb_ = &k_lds[half][nb][0];
    const bf16* vb_ = &v_lds[half][nb][0];

    f32x16v s0, s1;
    #pragma unroll
    for (int r=0;r<16;r++){ s0[r]=0.f; s1[r]=0.f; }
    __builtin_amdgcn_s_setprio(1);
    #pragma unroll
    for (int kc=0;kc<5;kc++){
      bf16x8v kf0 = *(const bf16x8v*)(kb_ + lbase + kc*1024);
      bf16x8v kf1 = *(const bf16x8v*)(kb_ + lbase + kc*1024 + 256);
      s0 = mfma32(kf0, qf[kc], s0);
      s1 = mfma32(kf1, qf[kc], s1);
    }
    __builtin_amdgcn_s_setprio(0);

    #pragma unroll
    for (int r=0;r<16;r++){ s0[r] = exp2f(s0[r]); s1[r] = exp2f(s1[r]); }

    float t0 = 0.f, t1 = 0.f;
    #pragma unroll
    for (int r=0;r<16;r++){ t0 += s0[r]; t1 += s1[r]; }
    float sum = t0 + t1;
    sum += __shfl_xor(sum, 32);
    lrow += sum;

    bf16x8v pa0, pa1, pa2, pa3;
    #pragma unroll
    for (int e=0;e<8;e++){
      pa0[e] = (bf16)s0[e];   pa1[e] = (bf16)s0[e+8];
      pa2[e] = (bf16)s1[e];   pa3[e] = (bf16)s1[e+8];
    }

    __builtin_amdgcn_s_setprio(1);
    #pragma unroll
    for (int m=0;m<4;m++){
      bf16x8v vf0 = *(const bf16x8v*)(vb_ + lbase + m*1024);
      bf16x8v vf1 = *(const bf16x8v*)(vb_ + lbase + m*1024 + 256);
      bf16x8v pm = (m==0)?pa0:(m==1)?pa1:(m==2)?pa2:pa3;
      oacc0 = mfma32(vf0, pm, oacc0);
      oacc1 = mfma32(vf1, pm, oacc1);
    }
    __builtin_amdgcn_s_setprio(0);
  };

  STAGE(0, 0);
  __syncthreads();
  int cur = 0;
  #pragma unroll 1
  for (int t=0; t<NTl; ++t){
    if (t+1 < NTl) STAGE(t+1, cur^1);
    COMPUTE(cur);
    __syncthreads();
    cur ^= 1;
  }

  // ---- in-block merge (plain sum; overlay k_lds) ----
  float* mrg = (float*)&k_lds[0][0][0];    // [q-row][68]: 64 O + l
  if (half == 1){
    float* row = mrg + (wl*32 + q5)*68;
    #pragma unroll
    for (int rq=0;rq<4;rq++){
      f32x4v t0v, t1v;
      #pragma unroll
      for (int k=0;k<4;k++){ t0v[k] = oacc0[rq*4+k]; t1v[k] = oacc1[rq*4+k]; }
      *(f32x4v*)(row + 0  + rq*8 + hi*4) = t0v;
      *(f32x4v*)(row + 32 + rq*8 + hi*4) = t1v;
    }
    if (hi == 0) row[64] = lrow;
  }
  __syncthreads();
  if (half == 0){
    const float* row = mrg + (wl*32 + q5)*68;
    const float inv = 1.0f / (lrow + row[64]);
    bf16* orow = &Og[(size_t)(b*SEQ + qrow)*D_MODEL + h*DKH];
    #pragma unroll
    for (int rq=0;rq<4;rq++){
      f32x4v o1a = *(const f32x4v*)(row + 0  + rq*8 + hi*4);
      f32x4v o1b = *(const f32x4v*)(row + 32 + rq*8 + hi*4);
      bf16x4v ov0, ov1;
      #pragma unroll
      for (int k=0;k<4;k++){
        ov0[k] = (bf16)((oacc0[rq*4+k] + o1a[k]) * inv);
        ov1[k] = (bf16)((oacc1[rq*4+k] + o1b[k]) * inv);
      }
      const int d = 8*rq + 4*hi;
      *(bf16x4v*)(orow + d)      = ov0;
      *(bf16x4v*)(orow + 32 + d) = ov1;
    }
  }
}

// ---------------- launch ----------------
extern "C" void kernel_launch(void* const* d_in, const int* in_sizes, int n_in,
                              void* d_out, int out_size, void* d_ws, size_t ws_size,
                              hipStream_t stream)
{
  (void)in_sizes; (void)n_in; (void)out_size; (void)ws_size;
  const float* x     = (const float*)d_in[0];
  const float* Wq    = (const float*)d_in[1];
  const float* bq    = (const float*)d_in[2];
  const float* Wk    = (const float*)d_in[3];
  const float* bk    = (const float*)d_in[4];
  const float* Wv    = (const float*)d_in[5];
  const float* bv    = (const float*)d_in[6];
  const float* Wo    = (const float*)d_in[7];
  const float* bo    = (const float*)d_in[8];
  const float* rbias = (const float*)d_in[9];
  const int*   rmask = (const int*)d_in[10];
  const int*   amask = (const int*)d_in[11];
  float* out = (float*)d_out;

  char* ws = (char*)d_ws;
  bf16*  xb    = (bf16*)(ws);                 //  8 MB
  bf16*  wqb   = (bf16*)(ws + (8u<<20));      //  2 MB each
  bf16*  wkb   = (bf16*)(ws + (10u<<20));
  bf16*  wvb   = (bf16*)(ws + (12u<<20));
  bf16*  wob   = (bf16*)(ws + (14u<<20));
  bf16*  qb    = (bf16*)(ws + (16u<<20));     // 10 MB Q' [b][h][s][80]
  bf16*  kb    = (bf16*)(ws + (27u<<20));     // 10 MB K' [b][h][s][80]
  bf16*  vtb   = (bf16*)(ws + (38u<<20));     //  8 MB V^T [b][h][dk][s]
  bf16*  aob   = (bf16*)(ws + (46u<<20));     //  8 MB attn out [s][e]

  convert_kernel<<<4096, 256, 0, stream>>>(x,Wq,Wk,Wv,Wo, xb,wqb,wkb,wvb,wob);

  GemmOuts qkv;
  qkv.W[0]=wqb; qkv.W[1]=wkb; qkv.W[2]=wvb;
  qkv.bia[0]=bq; qkv.bia[1]=bk; qkv.bia[2]=bv;
  qkv.out[0]=qb; qkv.out[1]=kb; qkv.out[2]=vtb;
  gemm_qkv_kernel<<<1280, 256, 0, stream>>>(xb, qkv, 0.125f*LOG2E,
                                            rbias, rmask, amask, qb, kb);

  attn10_kernel<<<512, 512, 0, stream>>>(qb, kb, vtb, aob);

  gemm_out_kernel<<<512, 256, 0, stream>>>(aob, wob, bo, out);
}